// Round 8
// baseline (397.284 us; speedup 1.0000x reference)
//
#include <hip/hip_runtime.h>

#define C_DIM 768

// d_ws layout:
//   [0)        8 x uint counts
//   [1024)     WaT4: granule (k4, o) -> float4 {Wa[o][4k4..+3]}, g = k4*192 + o
//              o in [0,168): Wa rows (a*56+e*8+r); o in [168,175): w_gate col e; else 0
//   [590848)   WbT4: granule (o, c4) -> float4 {WbT[o][4c4..+3]}, g = o*192 + c4, o = a*56+k
//   [1110016)  hT: float [168][T] -- scaled h^T, written by stage1, read by stage2

__global__ __launch_bounds__(256) void transpose_w(
    const float* __restrict__ wa, const float* __restrict__ wg,
    const float* __restrict__ wb,
    float4* __restrict__ waT4, float4* __restrict__ wbT4) {
  const int b = blockIdx.x;
  if (b < 144) {
    const int g = b * 256 + threadIdx.x;   // 192*192 = 36864
    const int o = g % 192, k4 = g / 192;
    float4 v = make_float4(0.f, 0.f, 0.f, 0.f);
    if (o < 168) {
      v = *(const float4*)(wa + (size_t)o * C_DIM + k4 * 4);
    } else if (o < 175) {
      const int e = o - 168;
      v.x = wg[(k4 * 4 + 0) * 7 + e];
      v.y = wg[(k4 * 4 + 1) * 7 + e];
      v.z = wg[(k4 * 4 + 2) * 7 + e];
      v.w = wg[(k4 * 4 + 3) * 7 + e];
    }
    waT4[g] = v;
  } else {
    const int g = (b - 144) * 256 + threadIdx.x;   // 168*192 = 32256 exactly
    const int c4 = g % 192, ak = g / 192;
    const int a = ak / 56, k = ak - a * 56;
    const int e = k >> 3, r = k & 7;
    const float* s = wb + ((size_t)(a * 7 + e) * C_DIM + c4 * 4) * 8 + r;
    wbT4[g] = make_float4(s[0], s[8], s[16], s[24]);
  }
}

// ---------------- Stage 1: h^T = scale(x @ WaT), routing ----------------
// 512 threads, 16 tokens/block, grid T/16 = 1024. 8 waves = (token-half th x
// k-quarter ki); per-wave inner loop identical to the round-7-verified one
// (acc[8][3], same fp32 FMA order -> bit-identical h). Round-8 changes:
// barriers/prologue amortized over 2x tokens, weight prefetch ring deepened
// to 3 (~576-cycle cover), x staged as a pure linear copy, hs stride 17
// (odd -> full 32-bank spread, 2-way max = free). LDS 62.3 KB -> 2 blocks/CU
// = 16 waves/CU (4/SIMD, vs 3.4 measured in round 7).
__global__ __launch_bounds__(512, 2) void stage1(
    const float* __restrict__ x, const float4* __restrict__ waT4,
    float* __restrict__ hT, unsigned int* __restrict__ counts, int T) {
  __shared__ float4 xw[2][8][192];   // 48 KB: [tok-half][tok][granule]
  __shared__ float hs[192 * 17];     // 13.1 KB: partial sums, stride 17
  __shared__ int bes[16];

  const int tid = threadIdx.x;
  const int w = tid >> 6, lane = tid & 63;
  const int ki = w & 3, th = w >> 2;
  const int t0 = blockIdx.x * 16;

  for (int g = tid; g < 192 * 17; g += 512) hs[g] = 0.f;

  // x staging: xw flat index f == x4 offset t0*192 + f  (pure linear copy)
  const float4* x4 = (const float4*)x;
  float4* xwf = (float4*)xw;
  #pragma unroll
  for (int j = 0; j < 6; ++j) {
    const int f = tid + 512 * j;   // 0..3071
    xwf[f] = x4[(size_t)t0 * 192 + f];
  }
  __syncthreads();

  float acc[8][3];
  #pragma unroll
  for (int t = 0; t < 8; ++t)
    #pragma unroll
    for (int m = 0; m < 3; ++m) acc[t][m] = 0.f;

  // lane covers o = lane + 64m (rows >=175 zero-padded); k ascending.
  const float4* wa_p = waT4 + (size_t)(ki * 48) * 192 + lane;
  float4 wv[3][3];
  #pragma unroll
  for (int r = 0; r < 3; ++r)
    #pragma unroll
    for (int m = 0; m < 3; ++m) wv[r][m] = wa_p[(size_t)r * 192 + 64 * m];

  #pragma unroll 3
  for (int s = 0; s < 48; ++s) {
    const int p = s % 3;
    #pragma unroll
    for (int t = 0; t < 8; ++t) {
      const float4 xv = xw[th][t][ki * 48 + s];   // wave-uniform broadcast
      #pragma unroll
      for (int m = 0; m < 3; ++m) {
        float v = acc[t][m];
        v = fmaf(xv.x, wv[p][m].x, v);
        v = fmaf(xv.y, wv[p][m].y, v);
        v = fmaf(xv.z, wv[p][m].z, v);
        v = fmaf(xv.w, wv[p][m].w, v);
        acc[t][m] = v;
      }
    }
    int sn = s + 3; sn = sn > 47 ? 47 : sn;  // prefetch s+3 (clamped tail)
    #pragma unroll
    for (int m = 0; m < 3; ++m) wv[p][m] = wa_p[(size_t)sn * 192 + 64 * m];
  }

  // k-quarter reduction: LDS float atomics. Banks (o*17+t)%32, 17 coprime 32
  // -> lanes 0..31 all-distinct banks, lane l vs l+32 2-way (free).
  #pragma unroll
  for (int m = 0; m < 3; ++m) {
    const int o = lane + 64 * m;
    #pragma unroll
    for (int t = 0; t < 8; ++t)
      atomicAdd(&hs[o * 17 + th * 8 + t], acc[t][m]);
  }
  __syncthreads();

  // argmax over logits rows 168..174 (thread = token), strict > tie-break
  if (tid < 16) {
    const int t = tid;
    float best = hs[168 * 17 + t];
    int b = 0;
    #pragma unroll
    for (int e = 1; e < 7; ++e) {
      const float lv = hs[(168 + e) * 17 + t];
      if (lv > best) { best = lv; b = e; }
    }
    bes[t] = b;
    atomicAdd(&counts[b], 1u);
  }
  __syncthreads();

  // scale by hierarchy coefficient, store h^T[o][t0+t]
  for (int g = tid; g < 168 * 16; g += 512) {
    const int o = g >> 4, t = g & 15;
    const int e = (o % 56) >> 3, b = bes[t];
    float co = (e == b) ? 1.f : 0.f;
    if (b >= 4 && e < 4) co += 0.25f;
    if (b == 6 && (e == 4 || e == 5)) co += 0.5f;
    hT[(size_t)o * T + t0 + t] = hs[o * 17 + t] * co;
  }
}

// ---------------- Stage 2: y[a] = h[a] @ WbT[a] ----------------
// grid (T/32, 3): block = (32 tokens, one adapter), 4 waves x 8 tokens.
// Round-8 change: weight prefetch ring deepened 2 -> 4 (k+4, ~256+ cycles
// in flight >= L2 latency; round-7's distance-2 left ~128 cycles of cover).
// acc[8] float4 + u[4] -> live ~75 VGPR, spill-proof. h tile staged once,
// zero barriers in the main loop.
__global__ __launch_bounds__(256, 2) void stage2(
    const float* __restrict__ hT, const float4* __restrict__ wbT4,
    float* __restrict__ out, int T) {
  __shared__ float hl[56][32];   // 7 KB

  const int tid = threadIdx.x;
  const int w = tid >> 6, lane = tid & 63;
  const int a = blockIdx.y;
  const int t0 = blockIdx.x * 32;
  const int tb = w * 8;

  for (int idx = tid; idx < 448; idx += 256) {   // 56 rows x 8 float4-cols
    const int k = idx >> 3, t4 = idx & 7;
    *(float4*)&hl[k][t4 * 4] =
        *(const float4*)&hT[(size_t)(a * 56 + k) * T + t0 + t4 * 4];
  }
  __syncthreads();

  const float4* wb_l = wbT4 + (size_t)(a * 56) * 192 + lane;
  float4* out4 = (float4*)out;

  #pragma unroll 1
  for (int cc = 0; cc < 3; ++cc) {
    const float4* wp = wb_l + cc * 64;
    float4 acc[8];
    #pragma unroll
    for (int t = 0; t < 8; ++t) acc[t] = make_float4(0.f, 0.f, 0.f, 0.f);

    float4 u[4];
    #pragma unroll
    for (int r = 0; r < 4; ++r) u[r] = wp[(size_t)r * 192];

    #pragma unroll 4
    for (int k = 0; k < 56; ++k) {
      const int p = k & 3;
      const float4 uu = u[p];
      int kn = k + 4; kn = kn > 55 ? 55 : kn;   // prefetch k+4 (clamped tail)
      u[p] = wp[(size_t)kn * 192];
      const float4 h0 = *(const float4*)&hl[k][tb];       // wave-uniform
      const float4 h1 = *(const float4*)&hl[k][tb + 4];
      const float hv[8] = {h0.x, h0.y, h0.z, h0.w, h1.x, h1.y, h1.z, h1.w};
      #pragma unroll
      for (int t = 0; t < 8; ++t) {
        const float s = hv[t];
        acc[t].x = fmaf(uu.x, s, acc[t].x);
        acc[t].y = fmaf(uu.y, s, acc[t].y);
        acc[t].z = fmaf(uu.z, s, acc[t].z);
        acc[t].w = fmaf(uu.w, s, acc[t].w);
      }
    }

    #pragma unroll
    for (int t = 0; t < 8; ++t)
      out4[((size_t)a * T + t0 + tb + t) * 192 + cc * 64 + lane] = acc[t];
  }
}

// loss = 2 * cv2(counts)  (importance == load == counts when K=1, gate==1.0)
__global__ void loss_k(const unsigned int* __restrict__ counts,
                       float* __restrict__ out, int T) {
  if (threadIdx.x == 0) {
    float c[7], mean = 0.f;
    #pragma unroll
    for (int e = 0; e < 7; ++e) { c[e] = (float)counts[e]; mean += c[e]; }
    mean *= (1.f / 7.f);
    float var = 0.f;
    #pragma unroll
    for (int e = 0; e < 7; ++e) { const float d = c[e] - mean; var += d * d; }
    var *= (1.f / 6.f);  // ddof=1
    out[(size_t)3 * T * C_DIM] = 2.f * (var / (mean * mean + 1e-10f));
  }
}

extern "C" void kernel_launch(void* const* d_in, const int* in_sizes, int n_in,
                              void* d_out, int out_size, void* d_ws, size_t ws_size,
                              hipStream_t stream) {
  const float* x  = (const float*)d_in[0];
  const float* wg = (const float*)d_in[1];
  const float* Wa = (const float*)d_in[2];
  const float* Wb = (const float*)d_in[3];
  float* out = (float*)d_out;

  unsigned int* counts = (unsigned int*)d_ws;
  float4* waT4 = (float4*)((char*)d_ws + 1024);
  float4* wbT4 = (float4*)((char*)d_ws + 590848);
  float* hT    = (float*)((char*)d_ws + 1110016);

  const int T = in_sizes[0] / C_DIM;  // 16384

  hipMemsetAsync(counts, 0, 8 * sizeof(unsigned int), stream);
  transpose_w<<<dim3(270), dim3(256), 0, stream>>>(Wa, wg, Wb, waT4, wbT4);
  stage1<<<dim3(T / 16), dim3(512), 0, stream>>>(x, waT4, hT, counts, T);
  stage2<<<dim3(T / 32, 3), dim3(256), 0, stream>>>(hT, wbT4, out, T);
  loss_k<<<dim3(1), dim3(64), 0, stream>>>(counts, out, T);
}